// Round 6
// baseline (323.154 us; speedup 1.0000x reference)
//
#include <hip/hip_runtime.h>
#include <hip/hip_bf16.h>

typedef unsigned short u16_t;
typedef unsigned int   u32_t;

#define B_ROWS  16384
#define D_IN    1024
#define D_OUT   512
#define NEXP    16
#define CNT_STRIDE 16   // pad each expert counter to its own 64B line (R2 post-mortem)
#define EPSF    2.2204460492503131e-16f
#define TAU     2.0e-3f // f32 logit-gap ambiguity threshold (err bound ~5e-6)
#define YBLOCKS 272     // max total row-blocks: 32768/128 + 16

using short8  = __attribute__((ext_vector_type(8))) short;
using floatx4 = __attribute__((ext_vector_type(4))) float;

__device__ __forceinline__ u16_t f2bf(float f) {
    u32_t u = __float_as_uint(f);
    u += 0x7fffu + ((u >> 16) & 1u);        // round-to-nearest-even
    return (u16_t)(u >> 16);
}

// ---------------------------------------------------------------------------
// Fused prep. blockIdx.x ranges:
//   [0, 8192)     x f32 -> bf16 row-major; block 0 zeroes counts+hdr.
//   [8192, 9216)  w_experts [e][k][n] -> wT [e][n][k] bf16 (LDS-tiled).
//   [9216, 9280)  w_router [D_IN][E] -> wrT [E][D_IN] f32.
// ---------------------------------------------------------------------------
__global__ __launch_bounds__(256) void prep_kernel(
        const float* __restrict__ x, const float* __restrict__ wr,
        const float* __restrict__ we,
        u16_t* __restrict__ xb, float* __restrict__ wrT,
        u16_t* __restrict__ wT, int* __restrict__ counts, int* __restrict__ hdr) {
    __shared__ u16_t sh[128][72];               // pad 64->72 (transpose tile)
    int blk = blockIdx.x;
    int t = threadIdx.x;
    if (blk < 8192) {
        if (blk == 0) { counts[t] = 0; if (t < 64) hdr[t] = 0; }
        size_t i = ((size_t)blk * 256 + t) * 8;
        float4 a = *(const float4*)(x + i);
        float4 b = *(const float4*)(x + i + 4);
        union { u16_t us[8]; uint4 v; } p;
        p.us[0] = f2bf(a.x); p.us[1] = f2bf(a.y); p.us[2] = f2bf(a.z); p.us[3] = f2bf(a.w);
        p.us[4] = f2bf(b.x); p.us[5] = f2bf(b.y); p.us[6] = f2bf(b.z); p.us[7] = f2bf(b.w);
        *(uint4*)(xb + i) = p.v;
    } else if (blk < 9216) {
        int b = blk - 8192;
        int e = b >> 6, k0 = ((b >> 3) & 7) * 128, n0 = (b & 7) * 64;
        int kk = t >> 4, nc = (t & 15) * 4;
        const float* src = we + ((size_t)e * D_IN + k0 + kk) * D_OUT + n0 + nc;
        #pragma unroll
        for (int p = 0; p < 8; ++p) {
            float4 v = *(const float4*)(src + (size_t)p * 16 * D_OUT);
            sh[p * 16 + kk][nc + 0] = f2bf(v.x);
            sh[p * 16 + kk][nc + 1] = f2bf(v.y);
            sh[p * 16 + kk][nc + 2] = f2bf(v.z);
            sh[p * 16 + kk][nc + 3] = f2bf(v.w);
        }
        __syncthreads();
        int nn = t >> 2, c = t & 3;             // 4 threads per n-row, 64B each
        u16_t* dst = wT + ((size_t)e * D_OUT + n0 + nn) * D_IN + k0 + c * 32;
        #pragma unroll
        for (int j = 0; j < 4; ++j) {
            union { u16_t us[8]; uint4 v; } p;
            #pragma unroll
            for (int jj = 0; jj < 8; ++jj) p.us[jj] = sh[c * 32 + j * 8 + jj][nn];
            *(uint4*)(dst + j * 8) = p.v;
        }
    } else {
        int i = (blk - 9216) * 256 + t;         // i = e*D_IN + d
        int e = i >> 10, d = i & 1023;
        wrT[i] = wr[d * NEXP + e];
    }
}

// ---------------------------------------------------------------------------
// Router pass 1, f32 (R5 post-mortem: f64+cvt made router ~50us VALU-bound).
// 32 rows/block, thread=(lr=t>>3, q=t&7), wrT staged in LDS. Rows whose
// top1-top2 or top2-top3 f32 gap < TAU are flagged for exact f64 redo in
// pass 2 (expected ~100 of 16384 rows); all other rows' selection is
// provably identical to the f64 reference (err << TAU). Hierarchical
// atomics as before.
// ---------------------------------------------------------------------------
__global__ __launch_bounds__(256) void router_f32(
        const float* __restrict__ x, const float* __restrict__ wrT,
        int* __restrict__ counts, int* __restrict__ rowlist,
        float* __restrict__ gatelist, int* __restrict__ hdr,
        int* __restrict__ flagrows) {
    __shared__ float wsh[NEXP * D_IN];          // 64 KB [e][d]
    __shared__ int hist[NEXP], base[NEXP], hist2[NEXP];
    __shared__ unsigned char eidx_sh[32][2];
    __shared__ float g_sh[32][2];

    int t = threadIdx.x;
    {   // stage wrT: 16384 floats / 256 threads = 16 float4 each
        const float4* src = (const float4*)wrT;
        float4* dst = (float4*)wsh;
        #pragma unroll
        for (int i = 0; i < 16; ++i) dst[t + 256 * i] = src[t + 256 * i];
    }
    if (t < NEXP) { hist[t] = 0; hist2[t] = 0; }
    __syncthreads();

    int lr = t >> 3, q = t & 7;
    int row = blockIdx.x * 32 + lr;
    const float4* xq = (const float4*)(x + (size_t)row * D_IN);

    float acc[NEXP];
    #pragma unroll
    for (int e = 0; e < NEXP; ++e) acc[e] = 0.f;

    for (int i = 0; i < 32; ++i) {
        float4 xv = xq[i * 8 + q];              // d = i*32 + q*4
        #pragma unroll
        for (int e = 0; e < NEXP; ++e) {
            float4 wv = *(const float4*)(&wsh[e * D_IN + i * 32 + q * 4]);
            acc[e] = fmaf(xv.x, wv.x, acc[e]);
            acc[e] = fmaf(xv.y, wv.y, acc[e]);
            acc[e] = fmaf(xv.z, wv.z, acc[e]);
            acc[e] = fmaf(xv.w, wv.w, acc[e]);
        }
    }
    #pragma unroll
    for (int e = 0; e < NEXP; ++e) {
        acc[e] += __shfl_xor(acc[e], 1);
        acc[e] += __shfl_xor(acc[e], 2);
        acc[e] += __shfl_xor(acc[e], 4);
    }
    if (q == 0) {
        // top-3 scan, stable (lower index wins ties) == jax.lax.top_k
        int i1 = 0; float v1 = acc[0];
        #pragma unroll
        for (int e = 1; e < NEXP; ++e) if (acc[e] > v1) { v1 = acc[e]; i1 = e; }
        int i2 = -1; float v2 = -3.0e38f;
        #pragma unroll
        for (int e = 0; e < NEXP; ++e) if (e != i1 && acc[e] > v2) { v2 = acc[e]; i2 = e; }
        float v3 = -3.0e38f;
        #pragma unroll
        for (int e = 0; e < NEXP; ++e) if (e != i1 && e != i2 && acc[e] > v3) v3 = acc[e];
        if ((v1 - v2 < TAU) || (v2 - v3 < TAU)) {
            int p = atomicAdd(&hdr[0], 1);      // rare (~100/16384)
            flagrows[p] = row;
            eidx_sh[lr][0] = 255; eidx_sh[lr][1] = 255;
        } else {
            float ed = __expf(v2 - v1);         // <= 1
            float s = 1.f + ed;
            eidx_sh[lr][0] = (unsigned char)i1; g_sh[lr][0] = 1.f / s;
            eidx_sh[lr][1] = (unsigned char)i2; g_sh[lr][1] = ed / s;
            atomicAdd(&hist[i1], 1);
            atomicAdd(&hist[i2], 1);
        }
    }
    __syncthreads();
    if (t < NEXP) base[t] = atomicAdd(&counts[t * CNT_STRIDE], hist[t]);
    __syncthreads();
    if (t < 64) {
        int r = t >> 1, sl = t & 1;
        int e = eidx_sh[r][sl];
        if (e != 255) {
            int pos = base[e] + atomicAdd(&hist2[e], 1);
            rowlist[e * B_ROWS + pos] = ((blockIdx.x * 32 + r) << 1) | sl;
            gatelist[e * B_ROWS + pos] = g_sh[r][sl];
        }
    }
}

// ---------------------------------------------------------------------------
// Router pass 2: exact f64 for flagged rows. One wave per row (lane: e=l&15,
// quarter=l>>4), 16 blocks x 4 waves stride the flag list. Appends straight
// to the global lists (few rows -> no contention).
// ---------------------------------------------------------------------------
__global__ __launch_bounds__(256) void router_fix(
        const float* __restrict__ x, const float* __restrict__ wrT,
        int* __restrict__ counts, int* __restrict__ rowlist,
        float* __restrict__ gatelist, const int* __restrict__ hdr,
        const int* __restrict__ flagrows) {
    int t = threadIdx.x, wv = t >> 6, lane = t & 63;
    int nflag = hdr[0];
    int e = lane & 15, qq = lane >> 4;
    for (int j = blockIdx.x * 4 + wv; j < nflag; j += 64) {
        int row = flagrows[j];
        const float* xr_ = x + (size_t)row * D_IN + qq * 256;
        const float* wr_ = wrT + (size_t)e * D_IN + qq * 256;
        double a0 = 0.0, a1 = 0.0;
        for (int i = 0; i < 128; ++i) {
            a0 += (double)xr_[2 * i]     * (double)wr_[2 * i];
            a1 += (double)xr_[2 * i + 1] * (double)wr_[2 * i + 1];
        }
        double acc = a0 + a1;
        acc += __shfl_xor(acc, 16);
        acc += __shfl_xor(acc, 32);
        int i1 = -1; double v1 = -1e300;
        for (int ee = 0; ee < NEXP; ++ee) {
            double tt = __shfl(acc, ee);
            if (tt > v1) { v1 = tt; i1 = ee; }
        }
        int i2 = -1; double v2 = -1e300;
        for (int ee = 0; ee < NEXP; ++ee) {
            double tt = __shfl(acc, ee);
            if (ee != i1 && tt > v2) { v2 = tt; i2 = ee; }
        }
        if (lane == 0) {
            double ed = exp(v2 - v1), s = 1.0 + ed;
            int p1 = atomicAdd(&counts[i1 * CNT_STRIDE], 1);
            rowlist[i1 * B_ROWS + p1] = (row << 1);
            gatelist[i1 * B_ROWS + p1] = (float)(1.0 / s);
            int p2 = atomicAdd(&counts[i2 * CNT_STRIDE], 1);
            rowlist[i2 * B_ROWS + p2] = (row << 1) | 1;
            gatelist[i2 * B_ROWS + p2] = (float)(ed / s);
        }
    }
}

// compact-grid head: map blockIdx.y -> (expert, ty) by scanning counts.
// R5 post-mortem: the (4,128,16) grid's active blocks all aliased onto the
// same ~64 CUs (512-stride == 0 mod 256) -> 3/4 of the machine idle.
__device__ __forceinline__ int map_yblock(const int* counts, int yc, int* ty) {
    int acc0 = 0;
    for (int e2 = 0; e2 < NEXP; ++e2) {
        int nb = (counts[e2 * CNT_STRIDE] + 127) >> 7;
        if (yc < acc0 + nb) { *ty = yc - acc0; return e2; }
        acc0 += nb;
    }
    return -1;
}

// ---------------------------------------------------------------------------
// Grouped expert GEMM (R5 body, compact grid). 128x128 tile, BK=32,
// mfma 16x16x32 bf16, 2x2 waves, fragment-order LDS (0 conflicts),
// VGPR-staged loads issued before the barrier.
// ---------------------------------------------------------------------------
template<bool USE_CONTRIB>
__global__ __launch_bounds__(256) void moe_gemm_bf16(
        const u16_t* __restrict__ xb, const u16_t* __restrict__ wT,
        const int* __restrict__ counts, const int* __restrict__ rowlist,
        const float* __restrict__ gatelist,
        float* __restrict__ out, float* __restrict__ contrib) {
    int ty;
    int e = map_yblock(counts, blockIdx.y, &ty);
    if (e < 0) return;
    int n_e = counts[e * CNT_STRIDE];
    int n0 = blockIdx.x * 128;

    // [tile(8)][q(4)][lm(16)] 16B chunks = 4096 u16 = 8 KB each
    __shared__ __align__(16) u16_t Af[4096];
    __shared__ __align__(16) u16_t Bf[4096];
    __shared__ int   rid_sh[128];
    __shared__ float gt_sh[128];

    int t = threadIdx.x;
    if (t < 128) {
        int gi = ty * 128 + t;
        int v = 0; float g = 0.f;
        if (gi < n_e) { v = rowlist[e * B_ROWS + gi]; g = gatelist[e * B_ROWS + gi]; }
        rid_sh[t] = v; gt_sh[t] = g;
    }
    __syncthreads();

    // staging: chunk c0 = t (tile=t>>6, q=(t>>4)&3, lm=t&15), c1 = t+256.
    int s_lm = t & 15, s_q = (t >> 4) & 3, s_tile = t >> 6;
    int rowA0 = s_tile * 16 + s_lm, rowA1 = rowA0 + 64;
    const u16_t* aG0 = xb + (size_t)(rid_sh[rowA0] >> 1) * D_IN + s_q * 8;
    const u16_t* aG1 = xb + (size_t)(rid_sh[rowA1] >> 1) * D_IN + s_q * 8;
    const u16_t* bG0 = wT + ((size_t)e * D_OUT + n0 + rowA0) * D_IN + s_q * 8;
    const u16_t* bG1 = wT + ((size_t)e * D_OUT + n0 + rowA1) * D_IN + s_q * 8;
    u16_t* aL0 = Af + t * 8;          // lane-linear 16B chunks
    u16_t* aL1 = Af + (t + 256) * 8;
    u16_t* bL0 = Bf + t * 8;
    u16_t* bL1 = Bf + (t + 256) * 8;

    int lane = t & 63, wv = t >> 6;
    int wm = wv >> 1, wn = wv & 1;
    int lm = lane & 15, q = lane >> 4;

    floatx4 acc[4][4];
    #pragma unroll
    for (int mi = 0; mi < 4; ++mi)
        #pragma unroll
        for (int ni = 0; ni < 4; ++ni)
            acc[mi][ni] = (floatx4){0.f, 0.f, 0.f, 0.f};

    for (int it = 0; it < D_IN / 32; ++it) {
        uint4 a0 = *(const uint4*)aG0;      // issued before barrier: latency
        uint4 a1 = *(const uint4*)aG1;      // overlaps other waves' compute
        uint4 b0 = *(const uint4*)bG0;
        uint4 b1 = *(const uint4*)bG1;
        aG0 += 32; aG1 += 32; bG0 += 32; bG1 += 32;

        __syncthreads();                    // prev iter's fragment reads done
        *(uint4*)aL0 = a0;
        *(uint4*)aL1 = a1;
        *(uint4*)bL0 = b0;
        *(uint4*)bL1 = b1;
        __syncthreads();                    // tiles resident

        short8 afr[4], bfr[4];
        #pragma unroll
        for (int mi = 0; mi < 4; ++mi)
            afr[mi] = *(const short8*)(Af + ((wm * 4 + mi) * 64 + lane) * 8);
        #pragma unroll
        for (int ni = 0; ni < 4; ++ni)
            bfr[ni] = *(const short8*)(Bf + ((wn * 4 + ni) * 64 + lane) * 8);
        #pragma unroll
        for (int mi = 0; mi < 4; ++mi)
            #pragma unroll
            for (int ni = 0; ni < 4; ++ni)
                acc[mi][ni] = __builtin_amdgcn_mfma_f32_16x16x32_bf16(
                    afr[mi], bfr[ni], acc[mi][ni], 0, 0, 0);
    }

    // epilogue: C/D layout col=lane&15, row=(lane>>4)*4+reg
    #pragma unroll
    for (int mi = 0; mi < 4; ++mi) {
        int rbase = wm * 64 + mi * 16 + q * 4;
        #pragma unroll
        for (int r = 0; r < 4; ++r) {
            int row = rbase + r;
            int gi = ty * 128 + row;
            bool ok = gi < n_e;
            int v = rid_sh[row];
            float g = gt_sh[row];
            size_t orow = (size_t)(v >> 1) * D_OUT;
            #pragma unroll
            for (int ni = 0; ni < 4; ++ni) {
                int c = n0 + wn * 64 + ni * 16 + lm;
                float val = g * __expf(acc[mi][ni][r]);
                if (ok) {
                    if (USE_CONTRIB) {
                        float* dst = (v & 1) ? contrib : out;
                        dst[orow + c] = val;
                    } else {
                        atomicAdd(&out[orow + c], val);
                    }
                }
            }
        }
    }
}

// ---------------------------------------------------------------------------
// Fallback f32-input GEMM (ws too small for bf16 buffers), compact grid.
// ---------------------------------------------------------------------------
template<bool USE_CONTRIB>
__global__ __launch_bounds__(256) void moe_gemm(
        const float* __restrict__ x, const float* __restrict__ w,
        const int* __restrict__ counts, const int* __restrict__ rowlist,
        const float* __restrict__ gatelist,
        float* __restrict__ out, float* __restrict__ contrib) {
    int ty;
    int e = map_yblock(counts, blockIdx.y, &ty);
    if (e < 0) return;
    int n_e = counts[e * CNT_STRIDE];
    int n0 = blockIdx.x * 128;

    __shared__ u16_t Ash[128][40];
    __shared__ u32_t Bsh[16][132];
    __shared__ int   rid_sh[128];
    __shared__ float gt_sh[128];

    int t = threadIdx.x;
    if (t < 128) {
        int gi = ty * 128 + t;
        int v = 0; float g = 0.f;
        if (gi < n_e) { v = rowlist[e * B_ROWS + gi]; g = gatelist[e * B_ROWS + gi]; }
        rid_sh[t] = v; gt_sh[t] = g;
    }
    __syncthreads();

    int ar = t >> 1, ah = t & 1;
    const float* xptr = x + (size_t)(rid_sh[ar] >> 1) * D_IN + ah * 16;
    int bkp = t >> 4, bng = t & 15;
    const float* wptr = w + (size_t)e * (D_IN * D_OUT)
                          + (size_t)(2 * bkp) * D_OUT + n0 + bng * 8;

    int lane = t & 63, wv = t >> 6;
    int wm = wv >> 1, wn = wv & 1;
    int lm = lane & 15, q = lane >> 4;

    floatx4 acc[4][4];
    #pragma unroll
    for (int mi = 0; mi < 4; ++mi)
        #pragma unroll
        for (int ni = 0; ni < 4; ++ni)
            acc[mi][ni] = (floatx4){0.f, 0.f, 0.f, 0.f};

    for (int it = 0; it < D_IN / 32; ++it) {
        float4 av0 = *(const float4*)(xptr + 0);
        float4 av1 = *(const float4*)(xptr + 4);
        float4 av2 = *(const float4*)(xptr + 8);
        float4 av3 = *(const float4*)(xptr + 12);
        xptr += 32;
        float4 b0 = *(const float4*)(wptr + 0);
        float4 b1 = *(const float4*)(wptr + 4);
        float4 b2 = *(const float4*)(wptr + D_OUT);
        float4 b3 = *(const float4*)(wptr + D_OUT + 4);
        wptr += 32 * D_OUT;

        __syncthreads();
        {
            union { u16_t us[16]; uint4 v[2]; } ap;
            float af[16] = {av0.x, av0.y, av0.z, av0.w, av1.x, av1.y, av1.z, av1.w,
                            av2.x, av2.y, av2.z, av2.w, av3.x, av3.y, av3.z, av3.w};
            #pragma unroll
            for (int j = 0; j < 16; ++j) ap.us[j] = f2bf(af[j]);
            *(uint4*)(&Ash[ar][ah * 16])     = ap.v[0];
            *(uint4*)(&Ash[ar][ah * 16 + 8]) = ap.v[1];
        }
        {
            union { u32_t up[8]; uint4 v[2]; } bp;
            bp.up[0] = (u32_t)f2bf(b0.x) | ((u32_t)f2bf(b2.x) << 16);
            bp.up[1] = (u32_t)f2bf(b0.y) | ((u32_t)f2bf(b2.y) << 16);
            bp.up[2] = (u32_t)f2bf(b0.z) | ((u32_t)f2bf(b2.z) << 16);
            bp.up[3] = (u32_t)f2bf(b0.w) | ((u32_t)f2bf(b2.w) << 16);
            bp.up[4] = (u32_t)f2bf(b1.x) | ((u32_t)f2bf(b3.x) << 16);
            bp.up[5] = (u32_t)f2bf(b1.y) | ((u32_t)f2bf(b3.y) << 16);
            bp.up[6] = (u32_t)f2bf(b1.z) | ((u32_t)f2bf(b3.z) << 16);
            bp.up[7] = (u32_t)f2bf(b1.w) | ((u32_t)f2bf(b3.w) << 16);
            *(uint4*)(&Bsh[bkp][bng * 8])     = bp.v[0];
            *(uint4*)(&Bsh[bkp][bng * 8 + 4]) = bp.v[1];
        }
        __syncthreads();

        short8 afr[4];
        #pragma unroll
        for (int mi = 0; mi < 4; ++mi)
            afr[mi] = *(const short8*)(&Ash[wm * 64 + mi * 16 + lm][q * 8]);
        short8 bfr[4];
        #pragma unroll
        for (int ni = 0; ni < 4; ++ni) {
            int nn = wn * 64 + ni * 16 + lm;
            union { uint4 u; short8 s; } cv;
            cv.u.x = Bsh[q * 4 + 0][nn];
            cv.u.y = Bsh[q * 4 + 1][nn];
            cv.u.z = Bsh[q * 4 + 2][nn];
            cv.u.w = Bsh[q * 4 + 3][nn];
            bfr[ni] = cv.s;
        }
        #pragma unroll
        for (int mi = 0; mi < 4; ++mi)
            #pragma unroll
            for (int ni = 0; ni < 4; ++ni)
                acc[mi][ni] = __builtin_amdgcn_mfma_f32_16x16x32_bf16(
                    afr[mi], bfr[ni], acc[mi][ni], 0, 0, 0);
    }

    #pragma unroll
    for (int mi = 0; mi < 4; ++mi) {
        int rbase = wm * 64 + mi * 16 + q * 4;
        #pragma unroll
        for (int r = 0; r < 4; ++r) {
            int row = rbase + r;
            int gi = ty * 128 + row;
            bool ok = gi < n_e;
            int v = rid_sh[row];
            float g = gt_sh[row];
            size_t orow = (size_t)(v >> 1) * D_OUT;
            #pragma unroll
            for (int ni = 0; ni < 4; ++ni) {
                int c = n0 + wn * 64 + ni * 16 + lm;
                float val = g * __expf(acc[mi][ni][r]);
                if (ok) {
                    if (USE_CONTRIB) {
                        float* dst = (v & 1) ? contrib : out;
                        dst[orow + c] = val;
                    } else {
                        atomicAdd(&out[orow + c], val);
                    }
                }
            }
        }
    }
}

// ---------------------------------------------------------------------------
// Combine: out = log(clamp(slot0 + slot1, eps))
// ---------------------------------------------------------------------------
__global__ __launch_bounds__(256) void combine_add_log(
        float* __restrict__ out, const float* __restrict__ contrib, int n4) {
    int i = blockIdx.x * blockDim.x + threadIdx.x;
    if (i >= n4) return;
    float4 a = ((const float4*)out)[i];
    float4 b = ((const float4*)contrib)[i];
    float4 r;
    float s;
    s = a.x + b.x; s = (s == 0.f) ? EPSF : s; r.x = __logf(s);
    s = a.y + b.y; s = (s == 0.f) ? EPSF : s; r.y = __logf(s);
    s = a.z + b.z; s = (s == 0.f) ? EPSF : s; r.z = __logf(s);
    s = a.w + b.w; s = (s == 0.f) ? EPSF : s; r.w = __logf(s);
    ((float4*)out)[i] = r;
}

__global__ __launch_bounds__(256) void log_inplace(float* __restrict__ out, int n4) {
    int i = blockIdx.x * blockDim.x + threadIdx.x;
    if (i >= n4) return;
    float4 a = ((float4*)out)[i];
    float4 r;
    float s;
    s = a.x; s = (s == 0.f) ? EPSF : s; r.x = __logf(s);
    s = a.y; s = (s == 0.f) ? EPSF : s; r.y = __logf(s);
    s = a.z; s = (s == 0.f) ? EPSF : s; r.z = __logf(s);
    s = a.w; s = (s == 0.f) ? EPSF : s; r.w = __logf(s);
    ((float4*)out)[i] = r;
}

// small transpose used only by fallback tiers
__global__ __launch_bounds__(256) void transpose_wr_k(
        const float* __restrict__ wr, float* __restrict__ wrT) {
    int i = blockIdx.x * 256 + threadIdx.x;
    int e = i >> 10, d = i & 1023;
    wrT[i] = wr[d * NEXP + e];
}

extern "C" void kernel_launch(void* const* d_in, const int* in_sizes, int n_in,
                              void* d_out, int out_size, void* d_ws, size_t ws_size,
                              hipStream_t stream) {
    const float* x  = (const float*)d_in[0];
    const float* wr = (const float*)d_in[1];
    const float* we = (const float*)d_in[2];
    float* out = (float*)d_out;
    char* ws = (char*)d_ws;

    size_t off = 0;
    int*   counts   = (int*)(ws + off);   off += 1024;                // 16 x 64B lines
    int*   hdr      = (int*)(ws + off);   off += 256;                 // [0]=nflag
    int*   flagrows = (int*)(ws + off);   off += (size_t)B_ROWS * 4;
    int*   rowlist  = (int*)(ws + off);   off += (size_t)NEXP * B_ROWS * 4;
    float* gates    = (float*)(ws + off); off += (size_t)NEXP * B_ROWS * 4;
    float* wrT      = (float*)(ws + off); off += (size_t)NEXP * D_IN * 4;
    float* contrib  = (float*)(ws + off); off += (size_t)B_ROWS * D_OUT * 4;
    size_t tier2_need = off;
    u16_t* xb       = (u16_t*)(ws + off); off += (size_t)B_ROWS * D_IN * 2;
    u16_t* wTb      = (u16_t*)(ws + off); off += (size_t)NEXP * D_IN * D_OUT * 2;
    size_t tier3_need = off;

    dim3 g(D_OUT / 128, YBLOCKS, 1);
    int n4 = B_ROWS * D_OUT / 4;

    if (ws_size >= tier3_need) {
        prep_kernel<<<9280, 256, 0, stream>>>(x, wr, we, xb, wrT, wTb, counts, hdr);
        router_f32<<<B_ROWS / 32, 256, 0, stream>>>(x, wrT, counts, rowlist, gates, hdr, flagrows);
        router_fix<<<16, 256, 0, stream>>>(x, wrT, counts, rowlist, gates, hdr, flagrows);
        moe_gemm_bf16<true><<<g, 256, 0, stream>>>(xb, wTb, counts, rowlist, gates, out, contrib);
        combine_add_log<<<(n4 + 255) / 256, 256, 0, stream>>>(out, contrib, n4);
    } else if (ws_size >= tier2_need) {
        hipMemsetAsync(counts, 0, 1280, stream);   // counts + hdr (adjacent)
        transpose_wr_k<<<NEXP * D_IN / 256, 256, 0, stream>>>(wr, wrT);
        router_f32<<<B_ROWS / 32, 256, 0, stream>>>(x, wrT, counts, rowlist, gates, hdr, flagrows);
        router_fix<<<16, 256, 0, stream>>>(x, wrT, counts, rowlist, gates, hdr, flagrows);
        moe_gemm<true><<<g, 256, 0, stream>>>(x, we, counts, rowlist, gates, out, contrib);
        combine_add_log<<<(n4 + 255) / 256, 256, 0, stream>>>(out, contrib, n4);
    } else {
        hipMemsetAsync(counts, 0, 1280, stream);
        transpose_wr_k<<<NEXP * D_IN / 256, 256, 0, stream>>>(wr, wrT);
        router_f32<<<B_ROWS / 32, 256, 0, stream>>>(x, wrT, counts, rowlist, gates, hdr, flagrows);
        router_fix<<<16, 256, 0, stream>>>(x, wrT, counts, rowlist, gates, hdr, flagrows);
        hipMemsetAsync(out, 0, (size_t)B_ROWS * D_OUT * 4, stream);
        moe_gemm<false><<<g, 256, 0, stream>>>(x, we, counts, rowlist, gates, out, nullptr);
        log_inplace<<<(n4 + 255) / 256, 256, 0, stream>>>(out, n4);
    }
}